// Round 1
// baseline (8563.493 us; speedup 1.0000x reference)
//
#include <hip/hip_runtime.h>
#include <hip/hip_cooperative_groups.h>

namespace cg = cooperative_groups;

#define HID    1024
#define DVID   4096
#define DWORD  512
#define NVOCAB 32000
#define NSTEP  39          // MAX_LEN - 1
#define NB     512         // blocks (2/CU on 256 CUs -> co-residency guaranteed)
#define NT     256         // threads per block
#define NWAVE  ((NB * NT) / 64)
#define NEG_BIG (-3.402823466e38f)

__device__ inline float fast_sigmoid(float x) { return 1.f / (1.f + __expf(-x)); }
__device__ inline float fast_tanh(float x)    { return 1.f - 2.f / (__expf(2.f * x) + 1.f); }

__device__ inline float wave_reduce(float v) {
#pragma unroll
    for (int o = 32; o; o >>= 1) v += __shfl_xor(v, o, 64);
    return v;
}

// combine two (max, sumexp) softmax partials
__device__ inline void smax_comb(float& M, float& S, float m2, float s2) {
    float nm = fmaxf(M, m2);
    S = S * __expf(M - nm) + s2 * __expf(m2 - nm);
    M = nm;
}

// one wave computes dot(w_row, x[0:len)); len multiple of 256; result on all lanes
__device__ inline float row_dot(const float* __restrict__ w, const float* x, int len, int lane) {
    float acc = 0.f;
    for (int q = lane * 4; q < len; q += 256) {
        float4 wv = *(const float4*)(w + q);
        float4 xv = *(const float4*)(x + q);
        acc = fmaf(wv.x, xv.x, acc);
        acc = fmaf(wv.y, xv.y, acc);
        acc = fmaf(wv.z, xv.z, acc);
        acc = fmaf(wv.w, xv.w, acc);
    }
    return wave_reduce(acc);
}

__global__ __launch_bounds__(NT) void seq2seq_kernel(
    const float* __restrict__ vid,
    const float* __restrict__ w_ih1, const float* __restrict__ w_hh1,
    const float* __restrict__ b_ih1, const float* __restrict__ b_hh1,
    const float* __restrict__ w_ih2, const float* __restrict__ w_hh2,
    const float* __restrict__ b_ih2, const float* __restrict__ b_hh2,
    const float* __restrict__ emb,  const float* __restrict__ w_out,
    const float* __restrict__ b_out,
    float* __restrict__ out, float* ws)
{
    cg::grid_group grid = cg::this_grid();
    const int tid  = threadIdx.x;
    const int lane = tid & 63;
    const int wib  = tid >> 6;                       // wave in block 0..3
    const int gw   = (blockIdx.x * NT + tid) >> 6;   // global wave id 0..NWAVE-1

    // workspace layout (floats)
    float* G1  = ws;              // 4096 gates of LSTM1
    float* G2  = ws + 4096;       // 4096 gates of LSTM2
    float* H1g = ws + 8192;       // 1024
    float* H2g = ws + 9216;       // 1024
    float* C1g = ws + 10240;      // [2][1024] double-buffered
    float* C2g = ws + 12288;      // [2][1024]
    float* PM  = ws + 14336;      // NB block softmax maxes
    float* PS  = PM + NB;         // NB block softmax sums
    int*   IDXp = (int*)(PS + NB);

    __shared__ float sVec[4096];   // vid / x-vector / h staging
    __shared__ float sH2o[1024];   // h2_old staging in phase B
    __shared__ float sRm[4], sRs[4];
    __shared__ int   sRi[4];

    //================ E1: gates1 = b_ih1 + b_hh1 + vid @ w_ih1 rows (h=0)
    for (int i = tid * 4; i < DVID; i += NT * 4)
        *(float4*)(sVec + i) = *(const float4*)(vid + i);
    if (blockIdx.x == 0 && tid == 0) *IDXp = 0;   // BOS
    __syncthreads();
    for (int r = gw; r < 4 * HID; r += NWAVE) {
        float v = row_dot(w_ih1 + (size_t)r * DVID, sVec, DVID, lane);
        if (lane == 0) G1[r] = v + b_ih1[r] + b_hh1[r];
    }
    grid.sync();

    //================ E2: h1/c1 from G1 (c_old=0); gates2 = b + [h1,0] @ w_ih2 (h2_old=0)
    for (int j = tid; j < HID; j += NT) {
        float gi = G1[j], gg = G1[j + 2 * HID], go = G1[j + 3 * HID];
        float cn = fast_sigmoid(gi) * fast_tanh(gg);      // c_old = 0
        float hn = fast_sigmoid(go) * fast_tanh(cn);
        sVec[j] = hn;
        if (blockIdx.x == 0) { C1g[j] = cn; H1g[j] = hn; }   // slot 0
    }
    for (int j = tid; j < DWORD; j += NT) sVec[HID + j] = 0.f;
    __syncthreads();
    for (int r = gw; r < 4 * HID; r += NWAVE) {
        float v = row_dot(w_ih2 + (size_t)r * (HID + DWORD), sVec, HID + DWORD, lane);
        if (lane == 0) G2[r] = v + b_ih2[r] + b_hh2[r];
    }
    grid.sync();

    //================ E3: h2/c2 from G2 (c_old=0)
    for (int j = tid; j < HID; j += NT) {
        float gi = G2[j], gg = G2[j + 2 * HID], go = G2[j + 3 * HID];
        float cn = fast_sigmoid(gi) * fast_tanh(gg);
        float hn = fast_sigmoid(go) * fast_tanh(cn);
        if (blockIdx.x == 0) { C2g[j] = cn; H2g[j] = hn; }   // slot 0
    }
    grid.sync();

    //================ decode loop
    for (int t = 0; t < NSTEP; ++t) {
        const int cslot = t & 1, nslot = cslot ^ 1;

        //---- Phase A: finalize softmax(t-1); gates1 = b + h1_old @ w_hh1 rows
        if (t > 0) {
            float M = NEG_BIG, S = 0.f;
            for (int i = tid; i < NB; i += NT) smax_comb(M, S, PM[i], PS[i]);
#pragma unroll
            for (int o = 32; o; o >>= 1) {
                float m2 = __shfl_xor(M, o, 64), s2 = __shfl_xor(S, o, 64);
                smax_comb(M, S, m2, s2);
            }
            if (lane == 0) { sRm[wib] = M; sRs[wib] = S; }
            __syncthreads();
            M = sRm[0]; S = sRs[0];
            for (int w = 1; w < NT / 64; ++w) smax_comb(M, S, sRm[w], sRs[w]);
            float off = M + __logf(S);
            float* orow = out + (size_t)(t - 1) * NVOCAB;
            for (int i = blockIdx.x * NT + tid; i < NVOCAB; i += NB * NT)
                orow[i] -= off;
            __syncthreads();
        }
        // stage h1_old
        for (int i = tid * 4; i < HID; i += NT * 4)
            *(float4*)(sVec + i) = *(const float4*)(H1g + i);
        __syncthreads();
        for (int r = gw; r < 4 * HID; r += NWAVE) {
            float v = row_dot(w_hh1 + (size_t)r * HID, sVec, HID, lane);
            if (lane == 0) G1[r] = v + b_ih1[r] + b_hh1[r];
        }
        grid.sync();

        //---- Phase B: h1/c1 update (block-redundant); gates2 = b + [h1,emb] @ w_ih2 + h2_old @ w_hh2
        for (int j = tid; j < HID; j += NT) {
            float gi = G1[j], gf = G1[j + HID], gg = G1[j + 2 * HID], go = G1[j + 3 * HID];
            float co = C1g[cslot * HID + j];
            float cn = fast_sigmoid(gf) * co + fast_sigmoid(gi) * fast_tanh(gg);
            float hn = fast_sigmoid(go) * fast_tanh(cn);
            sVec[j] = hn;
            if (blockIdx.x == 0) { C1g[nslot * HID + j] = cn; H1g[j] = hn; }
        }
        {
            const float* erow = emb + (size_t)(*IDXp) * DWORD;
            for (int j = tid; j < DWORD; j += NT) sVec[HID + j] = erow[j];
            for (int i = tid * 4; i < HID; i += NT * 4)
                *(float4*)(sH2o + i) = *(const float4*)(H2g + i);
        }
        __syncthreads();
        for (int r = gw; r < 4 * HID; r += NWAVE) {
            float v = row_dot(w_ih2 + (size_t)r * (HID + DWORD), sVec, HID + DWORD, lane)
                    + row_dot(w_hh2 + (size_t)r * HID, sH2o, HID, lane);
            if (lane == 0) G2[r] = v + b_ih2[r] + b_hh2[r];
        }
        grid.sync();

        //---- Phase C: h2/c2 update (block-redundant); argmax(h2) -> idx; logits + softmax partials
        for (int j = tid; j < HID; j += NT) {
            float gi = G2[j], gf = G2[j + HID], gg = G2[j + 2 * HID], go = G2[j + 3 * HID];
            float co = C2g[cslot * HID + j];
            float cn = fast_sigmoid(gf) * co + fast_sigmoid(gi) * fast_tanh(gg);
            float hn = fast_sigmoid(go) * fast_tanh(cn);
            sVec[j] = hn;
            if (blockIdx.x == 0) { C2g[nslot * HID + j] = cn; H2g[j] = hn; }
        }
        __syncthreads();
        // argmax over h2 (faithful to reference: topk over hidden, not logits)
        {
            float bm = NEG_BIG; int bi = 0;
            for (int j = tid; j < HID; j += NT) {
                float v = sVec[j];
                if (v > bm) { bm = v; bi = j; }
            }
#pragma unroll
            for (int o = 32; o; o >>= 1) {
                float vm = __shfl_xor(bm, o, 64); int vi = __shfl_xor(bi, o, 64);
                if (vm > bm || (vm == bm && vi < bi)) { bm = vm; bi = vi; }
            }
            if (lane == 0) { sRm[wib] = bm; sRi[wib] = bi; }
            __syncthreads();
            if (blockIdx.x == 0 && tid == 0) {
                float m0 = sRm[0]; int i0 = sRi[0];
                for (int w = 1; w < NT / 64; ++w)
                    if (sRm[w] > m0 || (sRm[w] == m0 && sRi[w] < i0)) { m0 = sRm[w]; i0 = sRi[w]; }
                *IDXp = i0;
            }
        }
        __syncthreads();   // protect sRm/sRs reuse below
        // logits rows + per-wave online (max, sumexp)
        {
            float* orow = out + (size_t)t * NVOCAB;
            float m = NEG_BIG, s = 0.f;
            for (int r = gw; r < NVOCAB; r += NWAVE) {
                float v = row_dot(w_out + (size_t)r * HID, sVec, HID, lane) + b_out[r];
                if (lane == 0) orow[r] = v;
                if (v > m) { s = s * __expf(m - v) + 1.f; m = v; }
                else        { s += __expf(v - m); }
            }
            if (lane == 0) { sRm[wib] = m; sRs[wib] = s; }
            __syncthreads();
            if (tid == 0) {
                float M = sRm[0], S = sRs[0];
                for (int w = 1; w < NT / 64; ++w) smax_comb(M, S, sRm[w], sRs[w]);
                PM[blockIdx.x] = M; PS[blockIdx.x] = S;
            }
        }
        grid.sync();
    }

    //================ finalize softmax for last step
    {
        float M = NEG_BIG, S = 0.f;
        for (int i = tid; i < NB; i += NT) smax_comb(M, S, PM[i], PS[i]);
#pragma unroll
        for (int o = 32; o; o >>= 1) {
            float m2 = __shfl_xor(M, o, 64), s2 = __shfl_xor(S, o, 64);
            smax_comb(M, S, m2, s2);
        }
        if (lane == 0) { sRm[wib] = M; sRs[wib] = S; }
        __syncthreads();
        M = sRm[0]; S = sRs[0];
        for (int w = 1; w < NT / 64; ++w) smax_comb(M, S, sRm[w], sRs[w]);
        float off = M + __logf(S);
        float* orow = out + (size_t)(NSTEP - 1) * NVOCAB;
        for (int i = blockIdx.x * NT + tid; i < NVOCAB; i += NB * NT)
            orow[i] -= off;
    }
}

extern "C" void kernel_launch(void* const* d_in, const int* in_sizes, int n_in,
                              void* d_out, int out_size, void* d_ws, size_t ws_size,
                              hipStream_t stream) {
    const float* vid   = (const float*)d_in[0];
    const float* w_ih1 = (const float*)d_in[1];
    const float* w_hh1 = (const float*)d_in[2];
    const float* b_ih1 = (const float*)d_in[3];
    const float* b_hh1 = (const float*)d_in[4];
    const float* w_ih2 = (const float*)d_in[5];
    const float* w_hh2 = (const float*)d_in[6];
    const float* b_ih2 = (const float*)d_in[7];
    const float* b_hh2 = (const float*)d_in[8];
    const float* emb   = (const float*)d_in[9];
    const float* w_out = (const float*)d_in[10];
    const float* b_out = (const float*)d_in[11];
    float* out = (float*)d_out;
    float* ws  = (float*)d_ws;

    void* args[] = { &vid, &w_ih1, &w_hh1, &b_ih1, &b_hh1,
                     &w_ih2, &w_hh2, &b_ih2, &b_hh2,
                     &emb, &w_out, &b_out, &out, &ws };
    hipLaunchCooperativeKernel((const void*)seq2seq_kernel,
                               dim3(NB), dim3(NT), args, 0, stream);
}